// Round 5
// baseline (298.336 us; speedup 1.0000x reference)
//
#include <hip/hip_runtime.h>
#include <hip/hip_fp16.h>

typedef unsigned short u16;
typedef unsigned int u32;
typedef __bf16 bf16x8 __attribute__((ext_vector_type(8)));
typedef float f32x4 __attribute__((ext_vector_type(4)));
typedef u32 u32x2 __attribute__((ext_vector_type(2)));
typedef __fp16 half2v __attribute__((ext_vector_type(2)));

// N_NODES=131072, IN_CHANNELS=256, NUM_PROJ=256, NUM_QUANT=256, NUM_GRAPHS=256
// nodes_per_graph = 512; scale = sqrt(256*256) = 256.
// Fully fused: per block = (graph g, p-half ph): GEMM 512x128x256 -> LDS packed fp16
// -> in-register bitonic sort (64 packed columns) -> quantile select -> out.

__device__ __forceinline__ u16 f2bf(float f) {
  union { float f; u32 u; } v; v.f = f;
  return (u16)((v.u + 0x7FFFu + ((v.u >> 16) & 1u)) >> 16);  // RNE
}
__device__ __forceinline__ u32 pk_rne(float a, float b) {
  union { float f; u32 u; } va, vb; va.f = a; vb.f = b;
  u32 ra = (va.u + 0x7FFFu + ((va.u >> 16) & 1u)) >> 16;
  u32 rb = (vb.u + 0x7FFFu + ((vb.u >> 16) & 1u)) & 0xFFFF0000u;
  return rb | ra;
}
// async global->LDS, 16B/lane; lds base wave-uniform, HW scatter = +lane*16
__device__ __forceinline__ void gl16(const void* g, void* l) {
  __builtin_amdgcn_global_load_lds((const __attribute__((address_space(1))) unsigned int*)g,
                                   (__attribute__((address_space(3))) unsigned int*)l,
                                   16, 0, 0);
}
__device__ __forceinline__ u32 pkmin(u32 a, u32 b) {
  u32 r; asm("v_pk_min_f16 %0, %1, %2" : "=v"(r) : "v"(a), "v"(b)); return r;
}
__device__ __forceinline__ u32 pkmax(u32 a, u32 b) {
  u32 r; asm("v_pk_max_f16 %0, %1, %2" : "=v"(r) : "v"(a), "v"(b)); return r;
}
template <int CTRL> __device__ __forceinline__ u32 xdpp(u32 x) {
  return (u32)__builtin_amdgcn_mov_dpp((int)x, CTRL, 0xF, 0xF, true);
}
template <int IMM> __device__ __forceinline__ u32 xswz(u32 x) {
  return (u32)__builtin_amdgcn_ds_swizzle((int)x, IMM);
}
#define EX_X1(x)  xdpp<0xB1>(x)      /* quad_perm [1,0,3,2]  = xor 1  */
#define EX_X2(x)  xdpp<0x4E>(x)      /* quad_perm [2,3,0,1]  = xor 2  */
#define EX_F3(x)  xdpp<0x1B>(x)      /* quad_perm [3,2,1,0]  = xor 3  */
#define EX_F7(x)  xdpp<0x141>(x)     /* half_mirror          = xor 7  */
#define EX_F15(x) xdpp<0x140>(x)     /* row_mirror           = xor 15 */
#define EX_X8(x)  xdpp<0x128>(x)     /* row_ror:8            = xor 8  */
#define EX_X4(x)  xswz<0x101F>(x)    /* swizzle xor 4  */
#define EX_X16(x) xswz<0x401F>(x)    /* swizzle xor 16 */
#define EX_F31(x) xswz<0x7C1F>(x)    /* swizzle xor 31 */
#define EX_F63(x) ((u32)__shfl_xor((int)(x), 63, 64))

#define LDS_BYTES 133120  // max(GEMM: 64K X + 66K padded A, sort: 64*518*4 = 129.5K)

__global__ __launch_bounds__(1024, 4) void fused_swe(const float* __restrict__ x,
                                                     const float* __restrict__ proj,
                                                     const float* __restrict__ cw,
                                                     float* __restrict__ out) {
  __shared__ __align__(16) char smem[LDS_BYTES];
  const int tid = threadIdx.x;
  const int lane = tid & 63;
  const int w = tid >> 6;       // wave 0..15
  const int q4 = lane >> 4;     // quad
  const int m16 = lane & 15;
  const int bid = blockIdx.x;
  const int g = bid & 255;      // graph; blocks (g,0),(g,1) are 256 apart -> same XCD
  const int ph = bid >> 8;      // p-half: p = ph*128 + [0,128)

  float* Xb = (float*)smem;          // [512 n][32 k] fp32 (per K-chunk, gl16-staged)
  u16* Ab = (u16*)(smem + 65536);    // [128 p][264 k] bf16 (padded: conflict-free frag reads)
  u32* sb = (u32*)smem;              // [64 pcol][518 n] packed fp16 pairs (aliases X+A)

  // ---- stage A once: proj[k][ph*128+p] fp32 -> Ab[p][k] bf16 ----
#pragma unroll
  for (int i = 0; i < 8; ++i) {
    const int id = tid + i * 1024;      // 0..8191
    const int k = id >> 5;              // 0..255
    const int pg = (id & 31) * 4;       // p-group of 4
    float4 f = *(const float4*)(proj + (size_t)k * 256 + ph * 128 + pg);
    Ab[(pg + 0) * 264 + k] = f2bf(f.x);
    Ab[(pg + 1) * 264 + k] = f2bf(f.y);
    Ab[(pg + 2) * 264 + k] = f2bf(f.z);
    Ab[(pg + 3) * 264 + k] = f2bf(f.w);
  }

  // x staging: round c stages rows [c*128, c*128+128) of this graph's 512
  const float* xsrc = x + ((size_t)g * 512 + (tid >> 3)) * 256 + (tid & 7) * 4;
  char* xdst = (char*)smem + w * 1024;

  f32x4 acc[2][8];
#pragma unroll
  for (int nt = 0; nt < 2; ++nt)
#pragma unroll
    for (int pt = 0; pt < 8; ++pt) acc[nt][pt] = (f32x4){0.f, 0.f, 0.f, 0.f};

  for (int ch = 0; ch < 8; ++ch) {
    const int k0 = ch * 32;
#pragma unroll
    for (int c = 0; c < 4; ++c)
      gl16(xsrc + (size_t)c * 128 * 256 + k0, xdst + c * 16384);
    __syncthreads();  // drains gl16 (vmcnt) + A-stage ds_writes (lgkm, first iter)

    // B-frags: 2 n-tiles, fp32 -> bf16 at read
    bf16x8 bfr[2];
#pragma unroll
    for (int nt = 0; nt < 2; ++nt) {
      const float* bp = Xb + (w * 32 + nt * 16 + m16) * 32 + q4 * 8;
      float4 f0 = *(const float4*)bp;
      float4 f1 = *(const float4*)(bp + 4);
      u32 pk[4] = { pk_rne(f0.x, f0.y), pk_rne(f0.z, f0.w),
                    pk_rne(f1.x, f1.y), pk_rne(f1.z, f1.w) };
      bfr[nt] = *(const bf16x8*)pk;
    }
    // A-frags streamed, both n-tiles per A read
#pragma unroll
    for (int pt = 0; pt < 8; ++pt) {
      bf16x8 af = *(const bf16x8*)&Ab[(pt * 16 + m16) * 264 + k0 + q4 * 8];
      acc[0][pt] = __builtin_amdgcn_mfma_f32_16x16x32_bf16(af, bfr[0], acc[0][pt], 0, 0, 0);
      acc[1][pt] = __builtin_amdgcn_mfma_f32_16x16x32_bf16(af, bfr[1], acc[1][pt], 0, 0, 0);
    }
    __syncthreads();  // X reads done before next-chunk staging overwrites
  }

  // ---- transition: acc (D: p=pt*16+q4*4+r, n=w*32+nt*16+m16) -> sb[pcol][n], pair (p, p+64)
#pragma unroll
  for (int nt = 0; nt < 2; ++nt)
#pragma unroll
    for (int pt4 = 0; pt4 < 4; ++pt4)
#pragma unroll
      for (int r = 0; r < 4; ++r) {
        union { half2v h; u32 u; } cv;
        cv.h = __builtin_amdgcn_cvt_pkrtz(acc[nt][pt4][r], acc[nt][pt4 + 4][r]);
        const int pcol = pt4 * 16 + q4 * 4 + r;
        const int n = w * 32 + nt * 16 + m16;
        sb[pcol * 518 + n] = cv.u;
      }
  __syncthreads();

  // ---- sort phase: each wave sorts 4 packed columns (2 groups each) in-register ----
#define CE(i, j) { u32 mn_ = pkmin(v[i], v[j]); u32 mx_ = pkmax(v[i], v[j]); v[i] = mn_; v[j] = mx_; }
#define INTRA3 \
  CE(0,4) CE(1,5) CE(2,6) CE(3,7) \
  CE(0,2) CE(1,3) CE(4,6) CE(5,7) \
  CE(0,1) CE(2,3) CE(4,5) CE(6,7)
#define FLIPP(EX, lowbit) { \
    const bool low_ = (lane & (lowbit)) == 0; \
    u32 t_[8]; \
    _Pragma("unroll") for (int r = 0; r < 8; ++r) t_[r] = EX(v[7 - r]); \
    _Pragma("unroll") for (int r = 0; r < 8; ++r) { \
      u32 mn_ = pkmin(v[r], t_[r]); u32 mx_ = pkmax(v[r], t_[r]); \
      v[r] = low_ ? mn_ : mx_; } }
#define XCROSSP(EX, lm) { \
    const bool low_ = (lane & (lm)) == 0; \
    _Pragma("unroll") for (int r = 0; r < 8; ++r) { \
      u32 t_ = EX(v[r]); \
      u32 mn_ = pkmin(v[r], t_); u32 mx_ = pkmax(v[r], t_); \
      v[r] = low_ ? mn_ : mx_; } }

  for (int s = 0; s < 4; ++s) {
    u32* col = sb + (w * 4 + s) * 518;
    u32 v[8];
#pragma unroll
    for (int r2 = 0; r2 < 4; ++r2)
      *(u32x2*)&v[r2 * 2] = *(const u32x2*)&col[lane * 8 + r2 * 2];

    // S=2
    CE(0,1) CE(2,3) CE(4,5) CE(6,7)
    // S=4
    CE(0,3) CE(1,2) CE(4,7) CE(5,6)
    CE(0,1) CE(2,3) CE(4,5) CE(6,7)
    // S=8
    CE(0,7) CE(1,6) CE(2,5) CE(3,4)
    CE(0,2) CE(1,3) CE(4,6) CE(5,7)
    CE(0,1) CE(2,3) CE(4,5) CE(6,7)
    // S=16
    FLIPP(EX_X1, 1)  INTRA3
    // S=32
    FLIPP(EX_F3, 2)  XCROSSP(EX_X1, 1)  INTRA3
    // S=64
    FLIPP(EX_F7, 4)  XCROSSP(EX_X2, 2) XCROSSP(EX_X1, 1)  INTRA3
    // S=128
    FLIPP(EX_F15, 8) XCROSSP(EX_X4, 4) XCROSSP(EX_X2, 2) XCROSSP(EX_X1, 1)  INTRA3
    // S=256
    FLIPP(EX_F31, 16) XCROSSP(EX_X8, 8) XCROSSP(EX_X4, 4) XCROSSP(EX_X2, 2) XCROSSP(EX_X1, 1)  INTRA3
    // S=512
    FLIPP(EX_F63, 32) XCROSSP(EX_X16, 16) XCROSSP(EX_X8, 8) XCROSSP(EX_X4, 4) XCROSSP(EX_X2, 2) XCROSSP(EX_X1, 1)  INTRA3

#pragma unroll
    for (int r2 = 0; r2 < 4; ++r2)
      *(u32x2*)&col[lane * 8 + r2 * 2] = *(const u32x2*)&v[r2 * 2];
  }
#undef CE
#undef INTRA3
#undef FLIPP
#undef XCROSSP
  __syncthreads();

  // ---- selection: out[g][q][ph*128+pl] = sorted[idx[q]] / 256 ----
  const float scale = 1.0f / 256.0f;
#pragma unroll 4
  for (int it = 0; it < 32; ++it) {
    const int linear = it * 1024 + tid;   // 0..32767
    const int q = linear >> 7;            // wave-uniform
    const int pl = linear & 127;
    const int iq = (int)floorf(cw[q] * 511.0f);
    const u32 val = sb[(pl & 63) * 518 + iq];
    const u16 h = (pl & 64) ? (u16)(val >> 16) : (u16)(val & 0xFFFF);
    __half_raw hr; hr.x = h;
    out[(size_t)g * 65536 + (size_t)q * 256 + ph * 128 + pl] = __half2float(__half(hr)) * scale;
  }
}

extern "C" void kernel_launch(void* const* d_in, const int* in_sizes, int n_in,
                              void* d_out, int out_size, void* d_ws, size_t ws_size,
                              hipStream_t stream) {
  const float* x    = (const float*)d_in[0];  // (131072, 256) fp32
  const float* proj = (const float*)d_in[1];  // (256, 256) fp32
  const float* cw   = (const float*)d_in[2];  // (256,) fp32
  float* out = (float*)d_out;                 // (256, 65536) fp32
  (void)d_ws; (void)ws_size;

  fused_swe<<<512, 1024, 0, stream>>>(x, proj, cw, out);
}